// Round 3
// baseline (422.883 us; speedup 1.0000x reference)
//
#include <hip/hip_runtime.h>

// Problem constants (match reference setup_inputs)
#define NSAMP  65536
#define DDIM   128
#define HWAVES 16384                 // persistent half-wave slots (2048 blocks x 8)
#define ITERS  (NSAMP / HWAVES)      // 4 samples per half-wave, grid-strided

// Half-wave (32 lanes) per sample; lane l owns elements {4l..4l+3} as float4.
// Software pipeline: while sample k's 7 row-gathers are in flight, prefetch
// sample k+1's indices — removes one exposed memory round-trip per sample and
// keeps the gather queue continuously occupied across the 4-sample loop.
// Projection is linear in x, so project (h + r - t) once per score.
__global__ __launch_bounds__(256) void transh_kernel(
    const int* __restrict__ pos_h, const int* __restrict__ pos_t, const int* __restrict__ pos_r,
    const int* __restrict__ neg_h, const int* __restrict__ neg_t, const int* __restrict__ neg_r,
    const float* __restrict__ ent, const float* __restrict__ vvrel, const float* __restrict__ bases,
    float* __restrict__ out)
{
    const int hw  = (blockIdx.x * blockDim.x + threadIdx.x) >> 5;  // half-wave id, 0..16383
    const int sub = threadIdx.x & 31;                              // lane within half-wave

    // indices for the first sample of this half-wave
    int ph_i = pos_h[hw];
    int pt_i = pos_t[hw];
    int pr_i = pos_r[hw];
    int nh_i = neg_h[hw];
    int nt_i = neg_t[hw];
    int nr_i = neg_r[hw];

    #pragma unroll
    for (int k = 0; k < ITERS; ++k) {
        const int s = hw + k * HWAVES;

        // ---- issue gathers: long-latency ent rows first, L2-resident tables last ----
        const float4 a  = ((const float4*)(ent   + (size_t)ph_i * DDIM))[sub];
        const float4 c  = ((const float4*)(ent   + (size_t)pt_i * DDIM))[sub];
        const float4 na = ((const float4*)(ent   + (size_t)nh_i * DDIM))[sub];
        const float4 nc = ((const float4*)(ent   + (size_t)nt_i * DDIM))[sub];
        const float4 v  = ((const float4*)(bases + (size_t)pr_i * DDIM))[sub];
        const float4 b  = ((const float4*)(vvrel + (size_t)pr_i * DDIM))[sub];
        const float4 nb = ((const float4*)(vvrel + (size_t)nr_i * DDIM))[sub];

        // ---- prefetch next sample's indices while the gathers are in flight ----
        if (k + 1 < ITERS) {
            const int s2 = s + HWAVES;
            ph_i = pos_h[s2];
            pt_i = pos_t[s2];
            pr_i = pos_r[s2];
            nh_i = neg_h[s2];
            nt_i = neg_t[s2];
            nr_i = neg_r[s2];
        }

        // ---- compute ----
        float4 sp, sn;
        sp.x = a.x + b.x - c.x;     sp.y = a.y + b.y - c.y;
        sp.z = a.z + b.z - c.z;     sp.w = a.w + b.w - c.w;
        sn.x = na.x + nb.x - nc.x;  sn.y = na.y + nb.y - nc.y;
        sn.z = na.z + nb.z - nc.z;  sn.w = na.w + nb.w - nc.w;

        float vv  = v.x * v.x  + v.y * v.y  + v.z * v.z  + v.w * v.w;
        float vsp = v.x * sp.x + v.y * sp.y + v.z * sp.z + v.w * sp.w;
        float vsn = v.x * sn.x + v.y * sn.y + v.z * sn.z + v.w * sn.w;

        // 32-lane butterfly (xor offsets <=16 stay within the half-wave)
        #pragma unroll
        for (int off = 16; off > 0; off >>= 1) {
            vv  += __shfl_xor(vv,  off, 64);
            vsp += __shfl_xor(vsp, off, 64);
            vsn += __shfl_xor(vsn, off, 64);
        }

        const float cp = vsp / vv;
        const float cn = vsn / vv;

        float ap = fabsf(sp.x - cp * v.x) + fabsf(sp.y - cp * v.y)
                 + fabsf(sp.z - cp * v.z) + fabsf(sp.w - cp * v.w);
        float an = fabsf(sn.x - cn * v.x) + fabsf(sn.y - cn * v.y)
                 + fabsf(sn.z - cn * v.z) + fabsf(sn.w - cn * v.w);

        #pragma unroll
        for (int off = 16; off > 0; off >>= 1) {
            ap += __shfl_xor(ap, off, 64);
            an += __shfl_xor(an, off, 64);
        }

        if (sub == 0) {
            out[s]         = ap;  // pos score
            out[NSAMP + s] = an;  // neg score
        }
    }
}

extern "C" void kernel_launch(void* const* d_in, const int* in_sizes, int n_in,
                              void* d_out, int out_size, void* d_ws, size_t ws_size,
                              hipStream_t stream) {
    const int*   pos_h = (const int*)d_in[0];
    const int*   pos_t = (const int*)d_in[1];
    const int*   pos_r = (const int*)d_in[2];
    const int*   neg_h = (const int*)d_in[3];
    const int*   neg_t = (const int*)d_in[4];
    const int*   neg_r = (const int*)d_in[5];
    const float* ent   = (const float*)d_in[6];
    const float* vvrel = (const float*)d_in[7];
    const float* bases = (const float*)d_in[8];
    float* out = (float*)d_out;

    // 16384 persistent half-waves, 4 samples each: 2048 blocks x 256 threads
    const int threads = 256;
    const int blocks  = (HWAVES * 32) / threads;  // 2048
    transh_kernel<<<blocks, threads, 0, stream>>>(
        pos_h, pos_t, pos_r, neg_h, neg_t, neg_r, ent, vvrel, bases, out);
}